// Round 19
// baseline (1348.622 us; speedup 1.0000x reference)
//
#include <hip/hip_runtime.h>
#include <cstdint>

#define STATE  64
#define DINNER 512

typedef __bf16  bf16x8 __attribute__((ext_vector_type(8)));
typedef float   f32x4  __attribute__((ext_vector_type(4)));
typedef float   f32x2  __attribute__((ext_vector_type(2)));

static __device__ __forceinline__ float sigmoidf_(float x){ return 1.f/(1.f+expf(-x)); }
static __device__ __forceinline__ float siluf_(float x){ return x/(1.f+expf(-x)); }
static __device__ __forceinline__ float softplusf_(float x){
    return fmaxf(x,0.f) + log1pf(expf(-fabsf(x)));
}
static __device__ __forceinline__ unsigned short f2bf(float f){
    unsigned int u = __float_as_uint(f);
    unsigned int r = (u + 0x7FFFu + ((u>>16)&1u)) >> 16;
    return (unsigned short)r;
}
static __device__ __forceinline__ float b2f(unsigned short s){
    return __uint_as_float(((unsigned int)s)<<16);
}
static __device__ __forceinline__ void gload16(const void* g, void* l){
    __builtin_amdgcn_global_load_lds(
        (const __attribute__((address_space(1))) void*)g,
        (__attribute__((address_space(3))) void*)l, 16, 0, 0);
}

// ---------------------------------------------------------------------------
// prep: build interleaved sequences (fp32 residual stream) for one bicms.
// ---------------------------------------------------------------------------
__global__ __launch_bounds__(64) void prep_k(const float* __restrict__ sem,
                                             const float* __restrict__ inst,
                                             float* __restrict__ xbuf, int bi)
{
    int u = blockIdx.x;
    int lane = threadIdx.x;
    int t; long n;
    if (bi == 0) {
        int s = u >> 7; t = u & 127;
        int b = s >> 5, r = s & 31; int w = t >> 1;
        n = (long)b*2048 + r*64 + w;
    } else {
        int s = u >> 6; t = u & 63;
        int b = s >> 6, w = s & 63; int hh = t >> 1;
        n = (long)b*2048 + hh*64 + w;
    }
    const float* src = ((t & 1) ? inst : sem) + n*256 + lane*4;
    float4 v = *(const float4*)src;
    *(float4*)(xbuf + (long)u*256 + lane*4) = v;
    *(float4*)(xbuf + ((long)16384 + u)*256 + lane*4) = v;
}

// ---------------------------------------------------------------------------
// LayerNorm over 256 dims, one wave per token.
// ---------------------------------------------------------------------------
template<bool BF16OUT>
__global__ __launch_bounds__(64) void ln_k(const float* __restrict__ x,
                                           void* __restrict__ outp,
                                           const float* __restrict__ sp,
                                           const float* __restrict__ bp,
                                           int pStride, int tokensPerZ)
{
    long tok = blockIdx.x;
    int z = (int)(tok / tokensPerZ);
    const float* s = sp + (long)z*pStride;
    const float* b = bp + (long)z*pStride;
    int lane = threadIdx.x;
    float4 v = *(const float4*)(x + tok*256 + lane*4);
    float sum = v.x+v.y+v.z+v.w;
    #pragma unroll
    for (int o=32;o>=1;o>>=1) sum += __shfl_xor(sum,o);
    float mu = sum * (1.f/256.f);
    float cx=v.x-mu, cy=v.y-mu, cz=v.z-mu, cw=v.w-mu;
    float vs = cx*cx+cy*cy+cz*cz+cw*cw;
    #pragma unroll
    for (int o=32;o>=1;o>>=1) vs += __shfl_xor(vs,o);
    float r = rsqrtf(vs*(1.f/256.f) + 1e-5f);
    float4 sv = *(const float4*)(s + lane*4);
    float4 bv = *(const float4*)(b + lane*4);
    float o0 = cx*r*sv.x + bv.x;
    float o1 = cy*r*sv.y + bv.y;
    float o2 = cz*r*sv.z + bv.z;
    float o3 = cw*r*sv.w + bv.w;
    if (BF16OUT) {
        ushort4 o4; o4.x=f2bf(o0); o4.y=f2bf(o1); o4.z=f2bf(o2); o4.w=f2bf(o3);
        *(ushort4*)((unsigned short*)outp + tok*256 + lane*4) = o4;
    } else {
        float4 o4; o4.x=o0; o4.y=o1; o4.z=o2; o4.w=o3;
        *(float4*)((float*)outp + tok*256 + lane*4) = o4;
    }
}

// ---------------------------------------------------------------------------
// Weight transpose + fp32->bf16: src [z][K][N] -> dst [z][dRowOff+N][dLd=K]
// ---------------------------------------------------------------------------
__global__ __launch_bounds__(256) void tcvt_k(const float* __restrict__ src,
                                              unsigned short* __restrict__ dst,
                                              int K, int N, long sStride, long dStride,
                                              int dRowOff, int dLd)
{
    __shared__ float t[32][33];
    int z = blockIdx.z;
    int n0 = blockIdx.x<<5, k0 = blockIdx.y<<5;
    int tx = threadIdx.x & 31, ty = threadIdx.x >> 5;
    const float* s = src + (long)z*sStride;
    #pragma unroll
    for (int i=0;i<4;i++) t[ty+8*i][tx] = s[(long)(k0+ty+8*i)*N + n0+tx];
    __syncthreads();
    unsigned short* d = dst + (long)z*dStride;
    #pragma unroll
    for (int i=0;i<4;i++)
        d[(long)(dRowOff + n0 + ty + 8*i)*dLd + k0 + tx] = f2bf(t[tx][ty+8*i]);
}

// ---------------------------------------------------------------------------
// MFMA bf16 GEMM, 64x128 tile, BK=32, 4 waves (2x2 over 32x64 sub-blocks),
// 2x4 fragments/wave. Fragment-linear LDS (conflict-free). 24 KB LDS ->
// ~6 blocks/CU; low VGPR -> high occupancy. 2-phase dbuf K-loop.
// (round-17 champion GEMM structure, separate per-output dispatches)
// ---------------------------------------------------------------------------
enum { EPI_SILU=0, EPI_SOFTPLUS=1, EPI_PLAINF=2, EPI_RES=3, EPI_GATE=4, EPI_BIAS=5 };

template<int MODE>
__global__ __launch_bounds__(256) void mgemm_k(
    const unsigned short* __restrict__ A, long aZ, int lda,
    const unsigned short* __restrict__ W, long wZ,
    float* __restrict__ Cf, unsigned short* __restrict__ Cb,
    int M, int K, int N,
    const float* __restrict__ p1, long s1,
    const float* __restrict__ p2,
    const float* __restrict__ p3)
{
    __shared__ __align__(16) unsigned short As[2][2048];   // 64 rows x 32 k
    __shared__ __align__(16) unsigned short Bs[2][4096];   // 128 rows x 32 k
    int z = blockIdx.z;
    const unsigned short* Az = A + (long)z*aZ;
    const unsigned short* Wz = W + (long)z*wZ;
    int bm = blockIdx.x<<6, bn = blockIdx.y<<7;
    int tid = threadIdx.x, w = tid>>6, lane = tid&63;
    int wm = w>>1, wn = w&1;
    int l15 = lane&15, l4 = lane>>4;

    f32x4 acc[2][4];
    #pragma unroll
    for (int i=0;i<2;i++)
        #pragma unroll
        for (int j=0;j<4;j++)
            acc[i][j] = (f32x4){0.f,0.f,0.f,0.f};

    auto stage = [&](int buf, int koff) {
        gload16(Az + (long)(bm + (w<<4) + l15)*lda + koff + (l4<<3), &As[buf][w<<9]);
        #pragma unroll
        for (int r = 0; r < 2; ++r) {
            int g = (r<<2) + w;
            gload16(Wz + (long)(bn + (g<<4) + l15)*K + koff + (l4<<3), &Bs[buf][g<<9]);
        }
    };

    stage(0, 0);
    __syncthreads();
    int nk = K >> 5;
    for (int t = 0; t < nk; ++t) {
        int cur = t & 1;
        if (t + 1 < nk) stage(cur ^ 1, (t + 1) << 5);
        bf16x8 a[2], b[4];
        #pragma unroll
        for (int i=0;i<2;i++)
            a[i] = *(const bf16x8*)&As[cur][(((wm<<1)+i)<<9) + (lane<<3)];
        #pragma unroll
        for (int j=0;j<4;j++)
            b[j] = *(const bf16x8*)&Bs[cur][(((wn<<2)+j)<<9) + (lane<<3)];
        #pragma unroll
        for (int i=0;i<2;i++)
            #pragma unroll
            for (int j=0;j<4;j++)
                acc[i][j] = __builtin_amdgcn_mfma_f32_16x16x32_bf16(a[i], b[j], acc[i][j], 0, 0, 0);
        __syncthreads();
    }

    #pragma unroll
    for (int i=0;i<2;i++){
        int row0 = bm + (wm<<5) + (i<<4) + (l4<<2);
        #pragma unroll
        for (int j=0;j<4;j++){
            int col = bn + (wn<<6) + (j<<4) + l15;
            #pragma unroll
            for (int tt=0;tt<4;tt++){
                int row = row0 + tt;
                long rowz = (long)z*M + row;
                float v = acc[i][j][tt];
                if (MODE == EPI_SILU) {
                    Cb[rowz*(long)N + col] = f2bf(siluf_(v));
                } else if (MODE == EPI_SOFTPLUS) {
                    Cb[rowz*(long)N + col] = f2bf(softplusf_(v + p1[(long)z*s1 + col]));
                } else if (MODE == EPI_PLAINF) {
                    Cf[rowz*(long)N + col] = v;
                } else if (MODE == EPI_RES) {
                    long rc = rowz*256 + col;
                    float o = Cf[rc] + v;              // x += g @ Wout (in-place)
                    Cf[rc] = o;
                    Cb[(long)row*512 + (z<<8) + col] = f2bf(o);   // interleaved [row][z*256+c]
                } else if (MODE == EPI_GATE) {
                    float gg = sigmoidf_(v + p3[col]);
                    long rl = (long)row*256 + col;
                    Cb[rl] = f2bf(gg*p1[rl] + (1.f-gg)*p2[rl]);
                } else { // EPI_BIAS
                    Cf[(long)row*256 + col] = v + p1[col];
                }
            }
        }
    }
}

// ---------------------------------------------------------------------------
// Selective scan v11 (round-18, confirmed win): 1-WAVE (64-thread) blocks +
// packed f32x2 math. 64-thread workgroups pack residency in 1-wave quanta
// (the 256-thread version was capped at ~3 blocks/CU regardless of grid).
//  - lane-halves: lanes 0-31 states 0-31, lanes 32-63 states 32-63 of the
//    same 32 d-channels (d = blockIdx.y*32 + lane&31); y via shfl_xor(32).
//  - packed f32x2 math (v_pk_fma_f32): 48 packed ops vs 96 scalar.
//  - private BC triple-buffer staged 2 ahead via global_load_lds;
//    s_waitcnt vmcnt(10) + sched_barrier(0) (5 vmem/step, in-order).
//  - dt bf16; 2-deep named register rotation; tail prefetches clamped.
//  - exp2f with Ad pre-scaled by log2(e); fused gating epilogue in-place.
// ---------------------------------------------------------------------------
__global__ __launch_bounds__(64) void scan_k(
    const unsigned short* __restrict__ dtq, const unsigned short* __restrict__ xs,
    unsigned short* zg,
    const float* __restrict__ BC,             // [tok][128] fp32: B|C
    const float* __restrict__ Alog, long aStride,
    const float* __restrict__ Dsk,
    int Bs, int Lint)
{
    __shared__ __align__(16) float bcs[3][128];
    int q = blockIdx.x;
    int stack = (q >= Bs) ? 1 : 0;
    int seq = q - stack*Bs;
    int lane = threadIdx.x;
    int dl = lane & 31;                  // d-channel within wave
    int sh = lane >> 5;                  // state half (0: s0-31, 1: s32-63)
    int d = (blockIdx.y << 5) + dl;
    float Ad  = -expf(Alog[(long)stack*aStride + d]) * 1.44269504088896340736f;
    float dsk = Dsk[(long)stack*aStride + d];
    long base = (long)stack*16384 + (long)seq*Lint;
    long tok  = stack ? (base + Lint - 1) : base;
    long step = stack ? -1 : 1;

    f32x2 hs2[16];
    #pragma unroll
    for (int s=0;s<16;s++) hs2[s] = (f32x2){0.f,0.f};

    // prologue: stage BC(t0)->buf0, BC(t1)->buf1; load operands t0, t1
    long t1 = (Lint > 1) ? tok + step : tok;
    if (lane < 32) {
        gload16(BC + tok*128 + (lane<<2), &bcs[0][lane<<2]);
        gload16(BC + t1*128  + (lane<<2), &bcs[1][lane<<2]);
    }
    float dvA = b2f(dtq[tok*DINNER + d]);
    float xvA = b2f(xs [tok*DINNER + d]);
    float zvA = b2f(zg [tok*DINNER + d]);
    float dvB = b2f(dtq[t1*DINNER + d]);
    float xvB = b2f(xs [t1*DINNER + d]);
    float zvB = b2f(zg [t1*DINNER + d]);

    int so = sh << 5;
    int cur = 0;
    for (int it = 0; it < Lint; ++it) {
        int sb = cur + 2; if (sb >= 3) sb -= 3;
        long tok2 = (it + 2 < Lint) ? tok + 2*step : tok;   // clamped
        if (lane < 32) gload16(BC + tok2*128 + (lane<<2), &bcs[sb][lane<<2]);
        float dvC = b2f(dtq[tok2*DINNER + d]);
        float xvC = b2f(xs [tok2*DINNER + d]);
        float zvC = b2f(zg [tok2*DINNER + d]);
        asm volatile("s_waitcnt vmcnt(10)" ::: "memory");   // 2-old BC stage retired
        __builtin_amdgcn_sched_barrier(0);

        float wdec = exp2f(dvA * Ad);
        float u = dvA * xvA;
        f32x2 w2 = (f32x2){wdec, wdec};
        f32x2 u2 = (f32x2){u, u};
        const float4* B4 = (const float4*)&bcs[cur][so];
        const float4* C4 = (const float4*)&bcs[cur][64 + so];
        f32x2 acc0 = (f32x2){0.f,0.f}, acc1 = (f32x2){0.f,0.f};
        #pragma unroll
        for (int s4=0; s4<8; ++s4){
            float4 bv = B4[s4], cv = C4[s4];
            f32x2 b0 = (f32x2){bv.x, bv.y}, b1 = (f32x2){bv.z, bv.w};
            f32x2 c0 = (f32x2){cv.x, cv.y}, c1 = (f32x2){cv.z, cv.w};
            int s0 = s4<<1;
            hs2[s0]   = __builtin_elementwise_fma(w2, hs2[s0],   u2*b0);
            acc0      = __builtin_elementwise_fma(hs2[s0],   c0, acc0);
            hs2[s0+1] = __builtin_elementwise_fma(w2, hs2[s0+1], u2*b1);
            acc1      = __builtin_elementwise_fma(hs2[s0+1], c1, acc1);
        }
        f32x2 accs = acc0 + acc1;
        float part = accs.x + accs.y;
        float yv = part + __shfl_xor(part, 32);
        if (sh == 0)
            zg[tok*DINNER + d] = f2bf((yv + dsk*xvA) * zvA);

        dvA=dvB; xvA=xvB; zvA=zvB;
        dvB=dvC; xvB=xvC; zvB=zvC;
        tok += step;
        cur = cur + 1; if (cur == 3) cur = 0;
    }
}

// ---------------------------------------------------------------------------
// Gather merged rows (bf16) into concat layout for the final merge GEMMs.
// ---------------------------------------------------------------------------
__global__ __launch_bounds__(64) void gather_k(const unsigned short* __restrict__ mh,
                                               const unsigned short* __restrict__ mv,
                                               unsigned short* __restrict__ catsem,
                                               unsigned short* __restrict__ catinst)
{
    int n = blockIdx.x;
    int lane = threadIdx.x;
    int b = n >> 11;
    int rem = n & 2047;
    int r = rem >> 6, w = rem & 63;
    long hrow = ((long)(b*32 + r)*128 + 2*w)*256;
    long vrow = ((long)(b*64 + w)*64  + 2*r)*256;
    ushort4 hsv = *(const ushort4*)(mh + hrow + lane*4);
    ushort4 vsv = *(const ushort4*)(mv + vrow + lane*4);
    ushort4 hiv = *(const ushort4*)(mh + hrow + 256 + lane*4);
    ushort4 viv = *(const ushort4*)(mv + vrow + 256 + lane*4);
    *(ushort4*)(catsem  + (long)n*512 +       lane*4) = hsv;
    *(ushort4*)(catsem  + (long)n*512 + 256 + lane*4) = vsv;
    *(ushort4*)(catinst + (long)n*512 +       lane*4) = hiv;
    *(ushort4*)(catinst + (long)n*512 + 256 + lane*4) = viv;
}

// ---------------------------------------------------------------------------
extern "C" void kernel_launch(void* const* d_in, const int* in_sizes, int n_in,
                              void* d_out, int out_size, void* d_ws, size_t ws_size,
                              hipStream_t stream)
{
    (void)in_sizes; (void)n_in; (void)out_size; (void)ws_size;
    const float* sem  = (const float*)d_in[0];
    const float* inst = (const float*)d_in[1];
    const float* Wx   = (const float*)d_in[2];
    const float* Wz   = (const float*)d_in[3];
    const float* Wdt  = (const float*)d_in[4];
    const float* WB   = (const float*)d_in[5];
    const float* WC   = (const float*)d_in[6];
    const float* Alog = (const float*)d_in[7];
    const float* Dsk  = (const float*)d_in[8];
    const float* dtb  = (const float*)d_in[9];
    const float* Wo   = (const float*)d_in[10];
    const float* lns  = (const float*)d_in[11];
    const float* lnb  = (const float*)d_in[12];
    const float* gW   = (const float*)d_in[13];
    const float* gb   = (const float*)d_in[14];
    const float* mW   = (const float*)d_in[15];
    const float* mb   = (const float*)d_in[16];
    const float* mlns = (const float*)d_in[17];
    const float* mlnb = (const float*)d_in[18];
    float* out = (float*)d_out;

    // ---- workspace layout (~227 MB, round-17 champion layout) ----
    char* base = (char*)d_ws;
    const long T2 = 32768;
    float* xbuf = (float*)base;                         base += T2*256*4;   // fp32 residual
    char* dtRegion = base;                              base += T2*512*4;   // dt bf16 / logits fp32 later
    unsigned short* xsb  = (unsigned short*)base;       base += T2*512*2;   // xs bf16; later cats/cati
    unsigned short* hb16 = (unsigned short*)base;       base += T2*256*2;   // LN output bf16
    unsigned short* gzb  = (unsigned short*)base;       base += T2*512*2;   // silu(z) -> g (in-place)
    char* xbcRegion = base;                             base += T2*128*4;   // bcf f32 / xb16 bf16 (time-shared)
    unsigned short* mh   = (unsigned short*)base;       base += (long)16384*256*2;
    unsigned short* mv   = (unsigned short*)base;       base += (long)16384*256*2;
    unsigned short* wxT  = (unsigned short*)base;       base += (long)8*512*256*2;
    unsigned short* wzT  = (unsigned short*)base;       base += (long)8*512*256*2;
    unsigned short* wdtT = (unsigned short*)base;       base += (long)8*512*256*2;
    unsigned short* woT  = (unsigned short*)base;       base += (long)8*256*512*2;
    unsigned short* wbc  = (unsigned short*)base;       base += (long)8*128*256*2;
    unsigned short* gwT  = (unsigned short*)base;       base += (long)2*256*512*2;
    unsigned short* mwT  = (unsigned short*)base;       base += (long)2*256*512*2;
    unsigned short* dt16 = (unsigned short*)dtRegion;   // [T2][512] bf16
    float* logits = (float*)dtRegion;                   // [8192][256] fp32 (after scans)
    float* bcf = (float*)xbcRegion;                     // [32768][128] fp32
    unsigned short* xb16 = (unsigned short*)xbcRegion;  // [16384][512] bf16 interleaved [row][z*256+c]
    unsigned short* cats = xsb;                         // [8192][512] bf16
    unsigned short* cati = xsb + (long)8192*512;

    dim3 t256(256);
    // ---- weights: transpose + bf16 (once per launch) ----
    tcvt_k<<<dim3(16,8,8), t256, 0, stream>>>(Wx,  wxT, 256, 512, 131072L, 131072L, 0, 256);
    tcvt_k<<<dim3(16,8,8), t256, 0, stream>>>(Wz,  wzT, 256, 512, 131072L, 131072L, 0, 256);
    tcvt_k<<<dim3(16,8,8), t256, 0, stream>>>(Wdt, wdtT,256, 512, 131072L, 131072L, 0, 256);
    tcvt_k<<<dim3(8,16,8), t256, 0, stream>>>(Wo,  woT, 512, 256, 131072L, 131072L, 0, 512);
    tcvt_k<<<dim3(2,8,8),  t256, 0, stream>>>(WB,  wbc, 256, 64,  16384L,  32768L,  0, 256);
    tcvt_k<<<dim3(2,8,8),  t256, 0, stream>>>(WC,  wbc, 256, 64,  16384L,  32768L, 64, 256);
    tcvt_k<<<dim3(8,16,2), t256, 0, stream>>>(gW,  gwT, 512, 256, 131072L, 131072L, 0, 512);
    tcvt_k<<<dim3(8,16,2), t256, 0, stream>>>(mW,  mwT, 512, 256, 131072L, 131072L, 0, 512);

    for (int bi = 0; bi < 2; ++bi) {
        int Bs   = (bi == 0) ? 128 : 256;
        int Lint = (bi == 0) ? 128 : 64;
        prep_k<<<dim3(16384), dim3(64), 0, stream>>>(sem, inst, xbuf, bi);

        for (int l = 0; l < 2; ++l) {
            long slOff = (long)bi*4 + l;     // weight-set base; +2 per z (stack)

            ln_k<true><<<dim3(32768), dim3(64), 0, stream>>>(
                xbuf, hb16, lns + slOff*256, lnb + slOff*256, 512, 16384);

            // xs = silu(h @ Wx) -> bf16
            mgemm_k<EPI_SILU><<<dim3(256,4,2), t256, 0, stream>>>(
                hb16, 16384L*256, 256, wxT + slOff*131072, 262144L,
                nullptr, xsb, 16384, 256, 512,
                nullptr, 0L, nullptr, nullptr);

            // silu(z) = silu(h @ Wz) -> bf16 (gating input for scan)
            mgemm_k<EPI_SILU><<<dim3(256,4,2), t256, 0, stream>>>(
                hb16, 16384L*256, 256, wzT + slOff*131072, 262144L,
                nullptr, gzb, 16384, 256, 512,
                nullptr, 0L, nullptr, nullptr);

            // dt = softplus(h @ Wdt + bias) -> bf16
            mgemm_k<EPI_SOFTPLUS><<<dim3(256,4,2), t256, 0, stream>>>(
                hb16, 16384L*256, 256, wdtT + slOff*131072, 262144L,
                nullptr, dt16, 16384, 256, 512,
                dtb + slOff*512, 1024L, nullptr, nullptr);

            // [B|C] = h @ [WB|WC] -> fp32 packed N=128
            mgemm_k<EPI_PLAINF><<<dim3(256,1,2), t256, 0, stream>>>(
                hb16, 16384L*256, 256, wbc + slOff*32768, 65536L,
                bcf, nullptr, 16384, 256, 128,
                nullptr, 0L, nullptr, nullptr);

            // selective scan + fused gating -> g (in-place over silu(z))
            scan_k<<<dim3(2*Bs,16), dim3(64), 0, stream>>>(
                dt16, xsb, gzb, bcf, Alog + slOff*512, 1024L,
                Dsk + slOff*512, Bs, Lint);

            // x += g @ Wout  (fp32 residual in-place + interleaved bf16 copy)
            mgemm_k<EPI_RES><<<dim3(256,2,2), t256, 0, stream>>>(
                gzb, 16384L*512, 512, woT + slOff*131072, 262144L,
                xbuf, xb16, 16384, 512, 256,
                nullptr, 0L, nullptr, nullptr);
        }

        // gate merge: sig([fwd,bwd]@gW+gb)*fwd + (1-.)*bwd -> bf16 mh/mv
        mgemm_k<EPI_GATE><<<dim3(256,2,1), t256, 0, stream>>>(
            xb16, 0L, 512, gwT + (long)bi*131072, 0L,
            nullptr, (bi ? mv : mh), 16384, 512, 256,
            xbuf, 0L, xbuf + (long)16384*256, gb + bi*256);
    }

    // gather concat rows; final merge GEMMs + LN -> d_out
    gather_k<<<dim3(8192), dim3(64), 0, stream>>>(mh, mv, cats, cati);
    for (int mi = 0; mi < 2; ++mi) {
        const unsigned short* cat = (mi == 0) ? cats : cati;
        mgemm_k<EPI_BIAS><<<dim3(128,2,1), t256, 0, stream>>>(
            cat, 0L, 512, mwT + (long)mi*131072, 0L,
            logits, nullptr, 8192, 512, 256,
            mb + mi*256, 0L, nullptr, nullptr);
        ln_k<false><<<dim3(8192), dim3(64), 0, stream>>>(
            logits, out + (long)mi*2097152, mlns + mi*256, mlnb + mi*256, 0, 8192);
    }
}

// Round 20
// 1308.301 us; speedup vs baseline: 1.0308x; 1.0308x over previous
//
#include <hip/hip_runtime.h>
#include <cstdint>

#define STATE  64
#define DINNER 512

typedef __bf16  bf16x8 __attribute__((ext_vector_type(8)));
typedef float   f32x4  __attribute__((ext_vector_type(4)));
typedef float   f32x2  __attribute__((ext_vector_type(2)));

static __device__ __forceinline__ float sigmoidf_(float x){ return 1.f/(1.f+expf(-x)); }
static __device__ __forceinline__ float siluf_(float x){ return x/(1.f+expf(-x)); }
static __device__ __forceinline__ float softplusf_(float x){
    return fmaxf(x,0.f) + log1pf(expf(-fabsf(x)));
}
static __device__ __forceinline__ unsigned short f2bf(float f){
    unsigned int u = __float_as_uint(f);
    unsigned int r = (u + 0x7FFFu + ((u>>16)&1u)) >> 16;
    return (unsigned short)r;
}
static __device__ __forceinline__ float b2f(unsigned short s){
    return __uint_as_float(((unsigned int)s)<<16);
}
static __device__ __forceinline__ void gload16(const void* g, void* l){
    __builtin_amdgcn_global_load_lds(
        (const __attribute__((address_space(1))) void*)g,
        (__attribute__((address_space(3))) void*)l, 16, 0, 0);
}

// ---------------------------------------------------------------------------
// prep: build interleaved sequences (fp32 residual stream) for one bicms.
// ---------------------------------------------------------------------------
__global__ __launch_bounds__(64) void prep_k(const float* __restrict__ sem,
                                             const float* __restrict__ inst,
                                             float* __restrict__ xbuf, int bi)
{
    int u = blockIdx.x;
    int lane = threadIdx.x;
    int t; long n;
    if (bi == 0) {
        int s = u >> 7; t = u & 127;
        int b = s >> 5, r = s & 31; int w = t >> 1;
        n = (long)b*2048 + r*64 + w;
    } else {
        int s = u >> 6; t = u & 63;
        int b = s >> 6, w = s & 63; int hh = t >> 1;
        n = (long)b*2048 + hh*64 + w;
    }
    const float* src = ((t & 1) ? inst : sem) + n*256 + lane*4;
    float4 v = *(const float4*)src;
    *(float4*)(xbuf + (long)u*256 + lane*4) = v;
    *(float4*)(xbuf + ((long)16384 + u)*256 + lane*4) = v;
}

// ---------------------------------------------------------------------------
// LayerNorm over 256 dims, one wave per token.
// ---------------------------------------------------------------------------
template<bool BF16OUT>
__global__ __launch_bounds__(64) void ln_k(const float* __restrict__ x,
                                           void* __restrict__ outp,
                                           const float* __restrict__ sp,
                                           const float* __restrict__ bp,
                                           int pStride, int tokensPerZ)
{
    long tok = blockIdx.x;
    int z = (int)(tok / tokensPerZ);
    const float* s = sp + (long)z*pStride;
    const float* b = bp + (long)z*pStride;
    int lane = threadIdx.x;
    float4 v = *(const float4*)(x + tok*256 + lane*4);
    float sum = v.x+v.y+v.z+v.w;
    #pragma unroll
    for (int o=32;o>=1;o>>=1) sum += __shfl_xor(sum,o);
    float mu = sum * (1.f/256.f);
    float cx=v.x-mu, cy=v.y-mu, cz=v.z-mu, cw=v.w-mu;
    float vs = cx*cx+cy*cy+cz*cz+cw*cw;
    #pragma unroll
    for (int o=32;o>=1;o>>=1) vs += __shfl_xor(vs,o);
    float r = rsqrtf(vs*(1.f/256.f) + 1e-5f);
    float4 sv = *(const float4*)(s + lane*4);
    float4 bv = *(const float4*)(b + lane*4);
    float o0 = cx*r*sv.x + bv.x;
    float o1 = cy*r*sv.y + bv.y;
    float o2 = cz*r*sv.z + bv.z;
    float o3 = cw*r*sv.w + bv.w;
    if (BF16OUT) {
        ushort4 o4; o4.x=f2bf(o0); o4.y=f2bf(o1); o4.z=f2bf(o2); o4.w=f2bf(o3);
        *(ushort4*)((unsigned short*)outp + tok*256 + lane*4) = o4;
    } else {
        float4 o4; o4.x=o0; o4.y=o1; o4.z=o2; o4.w=o3;
        *(float4*)((float*)outp + tok*256 + lane*4) = o4;
    }
}

// ---------------------------------------------------------------------------
// Weight transpose + fp32->bf16: src [z][K][N] -> dst [z][dRowOff+N][dLd=K]
// ---------------------------------------------------------------------------
__global__ __launch_bounds__(256) void tcvt_k(const float* __restrict__ src,
                                              unsigned short* __restrict__ dst,
                                              int K, int N, long sStride, long dStride,
                                              int dRowOff, int dLd)
{
    __shared__ float t[32][33];
    int z = blockIdx.z;
    int n0 = blockIdx.x<<5, k0 = blockIdx.y<<5;
    int tx = threadIdx.x & 31, ty = threadIdx.x >> 5;
    const float* s = src + (long)z*sStride;
    #pragma unroll
    for (int i=0;i<4;i++) t[ty+8*i][tx] = s[(long)(k0+ty+8*i)*N + n0+tx];
    __syncthreads();
    unsigned short* d = dst + (long)z*dStride;
    #pragma unroll
    for (int i=0;i<4;i++)
        d[(long)(dRowOff + n0 + ty + 8*i)*dLd + k0 + tx] = f2bf(t[tx][ty+8*i]);
}

// ---------------------------------------------------------------------------
// MFMA bf16 GEMM, 64x128 tile, BK=32, 4 waves (2x2 over 32x64 sub-blocks),
// 2x4 fragments/wave. Fragment-linear LDS (conflict-free). 24 KB LDS ->
// ~6 blocks/CU; low VGPR -> high occupancy. 2-phase dbuf K-loop.
// ---------------------------------------------------------------------------
enum { EPI_SILU=0, EPI_SOFTPLUS=1, EPI_PLAINF=2, EPI_RES=3, EPI_GATE=4, EPI_BIAS=5 };

template<int MODE>
__global__ __launch_bounds__(256) void mgemm_k(
    const unsigned short* __restrict__ A, long aZ, int lda,
    const unsigned short* __restrict__ W, long wZ,
    float* __restrict__ Cf, unsigned short* __restrict__ Cb,
    int M, int K, int N,
    const float* __restrict__ p1, long s1,
    const float* __restrict__ p2,
    const float* __restrict__ p3)
{
    __shared__ __align__(16) unsigned short As[2][2048];   // 64 rows x 32 k
    __shared__ __align__(16) unsigned short Bs[2][4096];   // 128 rows x 32 k
    int z = blockIdx.z;
    const unsigned short* Az = A + (long)z*aZ;
    const unsigned short* Wz = W + (long)z*wZ;
    int bm = blockIdx.x<<6, bn = blockIdx.y<<7;
    int tid = threadIdx.x, w = tid>>6, lane = tid&63;
    int wm = w>>1, wn = w&1;
    int l15 = lane&15, l4 = lane>>4;

    f32x4 acc[2][4];
    #pragma unroll
    for (int i=0;i<2;i++)
        #pragma unroll
        for (int j=0;j<4;j++)
            acc[i][j] = (f32x4){0.f,0.f,0.f,0.f};

    auto stage = [&](int buf, int koff) {
        gload16(Az + (long)(bm + (w<<4) + l15)*lda + koff + (l4<<3), &As[buf][w<<9]);
        #pragma unroll
        for (int r = 0; r < 2; ++r) {
            int g = (r<<2) + w;
            gload16(Wz + (long)(bn + (g<<4) + l15)*K + koff + (l4<<3), &Bs[buf][g<<9]);
        }
    };

    stage(0, 0);
    __syncthreads();
    int nk = K >> 5;
    for (int t = 0; t < nk; ++t) {
        int cur = t & 1;
        if (t + 1 < nk) stage(cur ^ 1, (t + 1) << 5);
        bf16x8 a[2], b[4];
        #pragma unroll
        for (int i=0;i<2;i++)
            a[i] = *(const bf16x8*)&As[cur][(((wm<<1)+i)<<9) + (lane<<3)];
        #pragma unroll
        for (int j=0;j<4;j++)
            b[j] = *(const bf16x8*)&Bs[cur][(((wn<<2)+j)<<9) + (lane<<3)];
        #pragma unroll
        for (int i=0;i<2;i++)
            #pragma unroll
            for (int j=0;j<4;j++)
                acc[i][j] = __builtin_amdgcn_mfma_f32_16x16x32_bf16(a[i], b[j], acc[i][j], 0, 0, 0);
        __syncthreads();
    }

    #pragma unroll
    for (int i=0;i<2;i++){
        int row0 = bm + (wm<<5) + (i<<4) + (l4<<2);
        #pragma unroll
        for (int j=0;j<4;j++){
            int col = bn + (wn<<6) + (j<<4) + l15;
            #pragma unroll
            for (int tt=0;tt<4;tt++){
                int row = row0 + tt;
                long rowz = (long)z*M + row;
                float v = acc[i][j][tt];
                if (MODE == EPI_SILU) {
                    Cb[rowz*(long)N + col] = f2bf(siluf_(v));
                } else if (MODE == EPI_SOFTPLUS) {
                    Cb[rowz*(long)N + col] = f2bf(softplusf_(v + p1[(long)z*s1 + col]));
                } else if (MODE == EPI_PLAINF) {
                    Cf[rowz*(long)N + col] = v;
                } else if (MODE == EPI_RES) {
                    long rc = rowz*256 + col;
                    float o = Cf[rc] + v;              // x += g @ Wout (in-place)
                    Cf[rc] = o;
                    Cb[(long)row*512 + (z<<8) + col] = f2bf(o);   // interleaved [row][z*256+c]
                } else if (MODE == EPI_GATE) {
                    float gg = sigmoidf_(v + p3[col]);
                    long rl = (long)row*256 + col;
                    Cb[rl] = f2bf(gg*p1[rl] + (1.f-gg)*p2[rl]);
                } else { // EPI_BIAS
                    Cf[(long)row*256 + col] = v + p1[col];
                }
            }
        }
    }
}

// ---------------------------------------------------------------------------
// Selective scan v10 (round-17 champion): 256-thread blocks, packed f32x2
// math (v_pk_fma_f32), barrier-free, 2-deep prefetch, bf16 dt.
//  - lane-halves: lanes 0-31 states 0-31, lanes 32-63 states 32-63 of the
//    same 32 d-channels; y via one __shfl_xor(part,32). Wave covers 32 d.
//  - per-wave PRIVATE BC triple-buffer in LDS staged 2 ahead via
//    global_load_lds; counted s_waitcnt vmcnt(10) + sched_barrier(0)
//    before the LDS reads (per-step vmem = 1 stage + 3 reg loads + 1 store
//    = 5; 2-old BC stage has >=10 newer ops; in-order retirement).
//  - B/C read as float4, repacked into f32x2 halves at register level.
//  - register operands 2-deep via named A/B/C rotation (SSA); tail
//    prefetches clamped (constant issue count).
//  - exp2f with Ad pre-scaled by log2(e).
//  - fused gating epilogue g = (y + Dskip*xs)*silu_z in-place over silu_z.
// ---------------------------------------------------------------------------
__global__ __launch_bounds__(256) void scan_k(
    const unsigned short* __restrict__ dtq, const unsigned short* __restrict__ xs,
    unsigned short* zg,
    const float* __restrict__ BC,             // [tok][128] fp32: B|C
    const float* __restrict__ Alog, long aStride,
    const float* __restrict__ Dsk,
    int Bs, int Lint)
{
    __shared__ __align__(16) float bcs[4][3][128];
    int q = blockIdx.x;
    int stack = (q >= Bs) ? 1 : 0;
    int seq = q - stack*Bs;
    int tid = threadIdx.x;
    int w = tid >> 6, lane = tid & 63;
    int dl = lane & 31;                  // d-channel within wave
    int sh = lane >> 5;                  // state half (0: s0-31, 1: s32-63)
    int d = (blockIdx.y << 7) + (w << 5) + dl;
    float Ad  = -expf(Alog[(long)stack*aStride + d]) * 1.44269504088896340736f;
    float dsk = Dsk[(long)stack*aStride + d];
    long base = (long)stack*16384 + (long)seq*Lint;
    long tok  = stack ? (base + Lint - 1) : base;
    long step = stack ? -1 : 1;

    f32x2 hs2[16];
    #pragma unroll
    for (int s=0;s<16;s++) hs2[s] = (f32x2){0.f,0.f};

    // prologue: stage BC(t0)->buf0, BC(t1)->buf1; load operands t0, t1
    long t1 = (Lint > 1) ? tok + step : tok;
    if (lane < 32) {
        gload16(BC + tok*128 + (lane<<2), &bcs[w][0][lane<<2]);
        gload16(BC + t1*128  + (lane<<2), &bcs[w][1][lane<<2]);
    }
    float dvA = b2f(dtq[tok*DINNER + d]);
    float xvA = b2f(xs [tok*DINNER + d]);
    float zvA = b2f(zg [tok*DINNER + d]);
    float dvB = b2f(dtq[t1*DINNER + d]);
    float xvB = b2f(xs [t1*DINNER + d]);
    float zvB = b2f(zg [t1*DINNER + d]);

    int so = sh << 5;
    int cur = 0;
    for (int it = 0; it < Lint; ++it) {
        int sb = cur + 2; if (sb >= 3) sb -= 3;
        long tok2 = (it + 2 < Lint) ? tok + 2*step : tok;   // clamped
        if (lane < 32) gload16(BC + tok2*128 + (lane<<2), &bcs[w][sb][lane<<2]);
        float dvC = b2f(dtq[tok2*DINNER + d]);
        float xvC = b2f(xs [tok2*DINNER + d]);
        float zvC = b2f(zg [tok2*DINNER + d]);
        asm volatile("s_waitcnt vmcnt(10)" ::: "memory");   // 2-old BC stage retired
        __builtin_amdgcn_sched_barrier(0);

        float wdec = exp2f(dvA * Ad);
        float u = dvA * xvA;
        f32x2 w2 = (f32x2){wdec, wdec};
        f32x2 u2 = (f32x2){u, u};
        const float4* B4 = (const float4*)&bcs[w][cur][so];
        const float4* C4 = (const float4*)&bcs[w][cur][64 + so];
        f32x2 acc0 = (f32x2){0.f,0.f}, acc1 = (f32x2){0.f,0.f};
        #pragma unroll
        for (int s4=0; s4<8; ++s4){
            float4 bv = B4[s4], cv = C4[s4];
            f32x2 b0 = (f32x2){bv.x, bv.y}, b1 = (f32x2){bv.z, bv.w};
            f32x2 c0 = (f32x2){cv.x, cv.y}, c1 = (f32x2){cv.z, cv.w};
            int s0 = s4<<1;
            hs2[s0]   = __builtin_elementwise_fma(w2, hs2[s0],   u2*b0);
            acc0      = __builtin_elementwise_fma(hs2[s0],   c0, acc0);
            hs2[s0+1] = __builtin_elementwise_fma(w2, hs2[s0+1], u2*b1);
            acc1      = __builtin_elementwise_fma(hs2[s0+1], c1, acc1);
        }
        f32x2 accs = acc0 + acc1;
        float part = accs.x + accs.y;
        float yv = part + __shfl_xor(part, 32);
        if (sh == 0)
            zg[tok*DINNER + d] = f2bf((yv + dsk*xvA) * zvA);

        dvA=dvB; xvA=xvB; zvA=zvB;
        dvB=dvC; xvB=xvC; zvB=zvC;
        tok += step;
        cur = cur + 1; if (cur == 3) cur = 0;
    }
}

// ---------------------------------------------------------------------------
// Gather merged rows (bf16) into concat layout for the final merge GEMMs.
// ---------------------------------------------------------------------------
__global__ __launch_bounds__(64) void gather_k(const unsigned short* __restrict__ mh,
                                               const unsigned short* __restrict__ mv,
                                               unsigned short* __restrict__ catsem,
                                               unsigned short* __restrict__ catinst)
{
    int n = blockIdx.x;
    int lane = threadIdx.x;
    int b = n >> 11;
    int rem = n & 2047;
    int r = rem >> 6, w = rem & 63;
    long hrow = ((long)(b*32 + r)*128 + 2*w)*256;
    long vrow = ((long)(b*64 + w)*64  + 2*r)*256;
    ushort4 hsv = *(const ushort4*)(mh + hrow + lane*4);
    ushort4 vsv = *(const ushort4*)(mv + vrow + lane*4);
    ushort4 hiv = *(const ushort4*)(mh + hrow + 256 + lane*4);
    ushort4 viv = *(const ushort4*)(mv + vrow + 256 + lane*4);
    *(ushort4*)(catsem  + (long)n*512 +       lane*4) = hsv;
    *(ushort4*)(catsem  + (long)n*512 + 256 + lane*4) = vsv;
    *(ushort4*)(catinst + (long)n*512 +       lane*4) = hiv;
    *(ushort4*)(catinst + (long)n*512 + 256 + lane*4) = viv;
}

// ---------------------------------------------------------------------------
extern "C" void kernel_launch(void* const* d_in, const int* in_sizes, int n_in,
                              void* d_out, int out_size, void* d_ws, size_t ws_size,
                              hipStream_t stream)
{
    (void)in_sizes; (void)n_in; (void)out_size; (void)ws_size;
    const float* sem  = (const float*)d_in[0];
    const float* inst = (const float*)d_in[1];
    const float* Wx   = (const float*)d_in[2];
    const float* Wz   = (const float*)d_in[3];
    const float* Wdt  = (const float*)d_in[4];
    const float* WB   = (const float*)d_in[5];
    const float* WC   = (const float*)d_in[6];
    const float* Alog = (const float*)d_in[7];
    const float* Dsk  = (const float*)d_in[8];
    const float* dtb  = (const float*)d_in[9];
    const float* Wo   = (const float*)d_in[10];
    const float* lns  = (const float*)d_in[11];
    const float* lnb  = (const float*)d_in[12];
    const float* gW   = (const float*)d_in[13];
    const float* gb   = (const float*)d_in[14];
    const float* mW   = (const float*)d_in[15];
    const float* mb   = (const float*)d_in[16];
    const float* mlns = (const float*)d_in[17];
    const float* mlnb = (const float*)d_in[18];
    float* out = (float*)d_out;

    // ---- workspace layout (~227 MB, champion layout) ----
    char* base = (char*)d_ws;
    const long T2 = 32768;
    float* xbuf = (float*)base;                         base += T2*256*4;   // fp32 residual
    char* dtRegion = base;                              base += T2*512*4;   // dt bf16 / logits fp32 later
    unsigned short* xsb  = (unsigned short*)base;       base += T2*512*2;   // xs bf16; later cats/cati
    unsigned short* hb16 = (unsigned short*)base;       base += T2*256*2;   // LN output bf16
    unsigned short* gzb  = (unsigned short*)base;       base += T2*512*2;   // silu(z) -> g (in-place)
    char* xbcRegion = base;                             base += T2*128*4;   // bcf f32 / xb16 bf16 (time-shared)
    unsigned short* mh   = (unsigned short*)base;       base += (long)16384*256*2;
    unsigned short* mv   = (unsigned short*)base;       base += (long)16384*256*2;
    unsigned short* wxT  = (unsigned short*)base;       base += (long)8*512*256*2;
    unsigned short* wzT  = (unsigned short*)base;       base += (long)8*512*256*2;
    unsigned short* wdtT = (unsigned short*)base;       base += (long)8*512*256*2;
    unsigned short* woT  = (unsigned short*)base;       base += (long)8*256*512*2;
    unsigned short* wbc  = (unsigned short*)base;       base += (long)8*128*256*2;
    unsigned short* gwT  = (unsigned short*)base;       base += (long)2*256*512*2;
    unsigned short* mwT  = (unsigned short*)base;       base += (long)2*256*512*2;
    unsigned short* dt16 = (unsigned short*)dtRegion;   // [T2][512] bf16
    float* logits = (float*)dtRegion;                   // [8192][256] fp32 (after scans)
    float* bcf = (float*)xbcRegion;                     // [32768][128] fp32
    unsigned short* xb16 = (unsigned short*)xbcRegion;  // [16384][512] bf16 interleaved [row][z*256+c]
    unsigned short* cats = xsb;                         // [8192][512] bf16
    unsigned short* cati = xsb + (long)8192*512;

    dim3 t256(256);
    // ---- weights: transpose + bf16 (once per launch) ----
    tcvt_k<<<dim3(16,8,8), t256, 0, stream>>>(Wx,  wxT, 256, 512, 131072L, 131072L, 0, 256);
    tcvt_k<<<dim3(16,8,8), t256, 0, stream>>>(Wz,  wzT, 256, 512, 131072L, 131072L, 0, 256);
    tcvt_k<<<dim3(16,8,8), t256, 0, stream>>>(Wdt, wdtT,256, 512, 131072L, 131072L, 0, 256);
    tcvt_k<<<dim3(8,16,8), t256, 0, stream>>>(Wo,  woT, 512, 256, 131072L, 131072L, 0, 512);
    tcvt_k<<<dim3(2,8,8),  t256, 0, stream>>>(WB,  wbc, 256, 64,  16384L,  32768L,  0, 256);
    tcvt_k<<<dim3(2,8,8),  t256, 0, stream>>>(WC,  wbc, 256, 64,  16384L,  32768L, 64, 256);
    tcvt_k<<<dim3(8,16,2), t256, 0, stream>>>(gW,  gwT, 512, 256, 131072L, 131072L, 0, 512);
    tcvt_k<<<dim3(8,16,2), t256, 0, stream>>>(mW,  mwT, 512, 256, 131072L, 131072L, 0, 512);

    for (int bi = 0; bi < 2; ++bi) {
        int Bs   = (bi == 0) ? 128 : 256;
        int Lint = (bi == 0) ? 128 : 64;
        prep_k<<<dim3(16384), dim3(64), 0, stream>>>(sem, inst, xbuf, bi);

        for (int l = 0; l < 2; ++l) {
            long slOff = (long)bi*4 + l;     // weight-set base; +2 per z (stack)

            ln_k<true><<<dim3(32768), dim3(64), 0, stream>>>(
                xbuf, hb16, lns + slOff*256, lnb + slOff*256, 512, 16384);

            // xs = silu(h @ Wx) -> bf16
            mgemm_k<EPI_SILU><<<dim3(256,4,2), t256, 0, stream>>>(
                hb16, 16384L*256, 256, wxT + slOff*131072, 262144L,
                nullptr, xsb, 16384, 256, 512,
                nullptr, 0L, nullptr, nullptr);

            // silu(z) = silu(h @ Wz) -> bf16 (gating input for scan)
            mgemm_k<EPI_SILU><<<dim3(256,4,2), t256, 0, stream>>>(
                hb16, 16384L*256, 256, wzT + slOff*131072, 262144L,
                nullptr, gzb, 16384, 256, 512,
                nullptr, 0L, nullptr, nullptr);

            // dt = softplus(h @ Wdt + bias) -> bf16
            mgemm_k<EPI_SOFTPLUS><<<dim3(256,4,2), t256, 0, stream>>>(
                hb16, 16384L*256, 256, wdtT + slOff*131072, 262144L,
                nullptr, dt16, 16384, 256, 512,
                dtb + slOff*512, 1024L, nullptr, nullptr);

            // [B|C] = h @ [WB|WC] -> fp32 packed N=128
            mgemm_k<EPI_PLAINF><<<dim3(256,1,2), t256, 0, stream>>>(
                hb16, 16384L*256, 256, wbc + slOff*32768, 65536L,
                bcf, nullptr, 16384, 256, 128,
                nullptr, 0L, nullptr, nullptr);

            // selective scan + fused gating -> g (in-place over silu(z))
            scan_k<<<dim3(2*Bs,4), t256, 0, stream>>>(
                dt16, xsb, gzb, bcf, Alog + slOff*512, 1024L,
                Dsk + slOff*512, Bs, Lint);

            // x += g @ Wout  (fp32 residual in-place + interleaved bf16 copy)
            mgemm_k<EPI_RES><<<dim3(256,2,2), t256, 0, stream>>>(
                gzb, 16384L*512, 512, woT + slOff*131072, 262144L,
                xbuf, xb16, 16384, 512, 256,
                nullptr, 0L, nullptr, nullptr);
        }

        // gate merge: sig([fwd,bwd]@gW+gb)*fwd + (1-.)*bwd -> bf16 mh/mv
        mgemm_k<EPI_GATE><<<dim3(256,2,1), t256, 0, stream>>>(
            xb16, 0L, 512, gwT + (long)bi*131072, 0L,
            nullptr, (bi ? mv : mh), 16384, 512, 256,
            xbuf, 0L, xbuf + (long)16384*256, gb + bi*256);
    }

    // gather concat rows; final merge GEMMs + LN -> d_out
    gather_k<<<dim3(8192), dim3(64), 0, stream>>>(mh, mv, cats, cati);
    for (int mi = 0; mi < 2; ++mi) {
        const unsigned short* cat = (mi == 0) ? cats : cati;
        mgemm_k<EPI_BIAS><<<dim3(128,2,1), t256, 0, stream>>>(
            cat, 0L, 512, mwT + (long)mi*131072, 0L,
            logits, nullptr, 8192, 512, 256,
            mb + mi*256, 0L, nullptr, nullptr);
        ln_k<false><<<dim3(8192), dim3(64), 0, stream>>>(
            logits, out + (long)mi*2097152, mlns + mi*256, mlnb + mi*256, 0, 8192);
    }
}